// Round 5
// baseline (587.437 us; speedup 1.0000x reference)
//
#include <hip/hip_runtime.h>
#include <hip/hip_bf16.h>
#include <cstdint>
#include <cstddef>

#define HW    262144          // 512*512
#define C     64
#define K     19
#define NPIX  1048576
#define TAUINV (1.0f / 0.07f)
#define EPS   1e-12f

// ws layout:
//   +0     unsigned num_pos
//   +4     float    loss_sum
//   +256   float    k0p[32*64]   (8 KB, classes padded to 32)
//   +8448  float    k0n[19*64]
//   +65536 unsigned pm[NPIX]     (4 MB)

typedef __attribute__((ext_vector_type(8))) short bf16x8;
typedef __attribute__((ext_vector_type(4))) float f32x4;

__device__ __forceinline__ float wave_reduce_f32(float v) {
#pragma unroll
    for (int off = 32; off; off >>= 1) v += __shfl_down(v, off);
    return v;
}
__device__ __forceinline__ unsigned wave_reduce_u32(unsigned v) {
#pragma unroll
    for (int off = 32; off; off >>= 1) v += __shfl_down(v, off);
    return v;
}

// packed RNE f32x2 -> bf16x2 (v_cvt_pk_bf16_f32)
__device__ __forceinline__ short2 pk_bf16(float a, float b) {
    union { __hip_bfloat162 bf; short2 s; } u;
    u.bf = __float22bfloat162_rn(make_float2(a, b));
    return u.s;
}
__device__ __forceinline__ float bf2f(short s) {
    return __uint_as_float((unsigned)(unsigned short)s << 16);
}

// 8 floats -> hi/lo bf16x8 (hi + lo reproduces f to ~2^-17 rel)
__device__ __forceinline__ void split8(const float4 x, const float4 y,
                                       bf16x8& h, bf16x8& l) {
    const short2 h01 = pk_bf16(x.x, x.y), h23 = pk_bf16(x.z, x.w);
    const short2 h45 = pk_bf16(y.x, y.y), h67 = pk_bf16(y.z, y.w);
    const short2 l01 = pk_bf16(x.x - bf2f(h01.x), x.y - bf2f(h01.y));
    const short2 l23 = pk_bf16(x.z - bf2f(h23.x), x.w - bf2f(h23.y));
    const short2 l45 = pk_bf16(y.x - bf2f(h45.x), y.y - bf2f(h45.y));
    const short2 l67 = pk_bf16(y.z - bf2f(h67.x), y.w - bf2f(h67.y));
    h[0] = h01.x; h[1] = h01.y; h[2] = h23.x; h[3] = h23.y;
    h[4] = h45.x; h[5] = h45.y; h[6] = h67.x; h[7] = h67.y;
    l[0] = l01.x; l[1] = l01.y; l[2] = l23.x; l[3] = l23.y;
    l[4] = l45.x; l[5] = l45.y; l[6] = l67.x; l[7] = l67.y;
}

// ---------------- Kernel 0: packed masks + num_pos ------------------------
// 4 px/thread, int4 gt loads (19 in flight), uint4 pm store.
__global__ __launch_bounds__(256) void k0_mask(
    const int* __restrict__ gt, unsigned* __restrict__ pm,
    unsigned* __restrict__ num_pos)
{
    const int g   = blockIdx.x * 256 + threadIdx.x;   // 0..262143
    const int px0 = g << 2;
    const int b   = px0 >> 18;
    const int hw  = px0 & (HW - 1);
    const int* gp = gt + (size_t)b * K * HW + hw;

    unsigned m0 = 0, m1 = 0, m2 = 0, m3 = 0;
#pragma unroll
    for (int k = 0; k < K; ++k) {
        const int4 gv = *(const int4*)(gp + (size_t)k * HW);
        m0 |= (gv.x == 1) ? (1u << k) : 0u;
        m1 |= (gv.y == 1) ? (1u << k) : 0u;
        m2 |= (gv.z == 1) ? (1u << k) : 0u;
        m3 |= (gv.w == 1) ? (1u << k) : 0u;
    }
    *(uint4*)(pm + px0) = make_uint4(m0, m1, m2, m3);

    unsigned np = __popc(m0) + __popc(m1) + __popc(m2) + __popc(m3);
    np = wave_reduce_u32(np);
    if ((threadIdx.x & 63) == 0) atomicAdd(num_pos, np);
}

// ---------------- Kernel 1: MFMA prototypes k0p[32][64] -------------------
// Wave owns one 64-px column set: hw0 = wave_id*64, chunk j = batch j.
// Per chunk: 1 pm dword + 16 feat dwordx4 (B-fragment order), 32 MFMAs.
// Next chunk's loads are interleaved into the nt loop (register prefetch).
__global__ __launch_bounds__(256, 3) void k1_proto(
    const float* __restrict__ feat, const unsigned* __restrict__ pm,
    float* __restrict__ k0p)
{
    __shared__ float red[32 * 64];
    const int tid  = threadIdx.x;
    const int lane = tid & 63;
    const int wv   = tid >> 6;
    const int q    = lane >> 4;
    const int n    = lane & 15;
    const int q8   = q << 3;
    const int wave_id = blockIdx.x * 4 + wv;          // 0..4095

    f32x4 acc[2][4];
#pragma unroll
    for (int mt = 0; mt < 2; ++mt)
#pragma unroll
        for (int nt = 0; nt < 4; ++nt)
            acc[mt][nt] = (f32x4){0.f, 0.f, 0.f, 0.f};

    const int hw0 = wave_id << 6;
    const float* fb = feat + (size_t)hw0 + (size_t)n * HW + q8;
    const unsigned* pmp = pm + (size_t)wave_id * 64 + lane;

    float4   F[16];
    unsigned mreg;

    // initial prefetch: chunk j=0 (batch 0)
#pragma unroll
    for (int nt = 0; nt < 4; ++nt)
#pragma unroll
        for (int kh = 0; kh < 2; ++kh) {
            const float* p = fb + (size_t)(nt * 16) * HW + kh * 32;
            F[nt * 4 + kh * 2 + 0] = *(const float4*)p;
            F[nt * 4 + kh * 2 + 1] = *(const float4*)(p + 4);
        }
    mreg = *pmp;

#pragma unroll
    for (int j = 0; j < 4; ++j) {
        // ---- A fragments from masks: A[kh][mt], k = q*8+jj, m = n+mt*16
        bf16x8 A[2][2];
#pragma unroll
        for (int jj = 0; jj < 8; ++jj) {
            const unsigned ma = __shfl(mreg, q8 + jj);        // px half 0
            const unsigned mb = __shfl(mreg, 32 + q8 + jj);   // px half 1
            A[0][0][jj] = (short)(((ma >> n) & 1u) * 0x3F80u);
            A[0][1][jj] = (short)(((ma >> (n + 16)) & 1u) * 0x3F80u);
            A[1][0][jj] = (short)(((mb >> n) & 1u) * 0x3F80u);
            A[1][1][jj] = (short)(((mb >> (n + 16)) & 1u) * 0x3F80u);
        }
        if (j < 3) mreg = pmp[(j + 1) * (NPIX / 4)];
        const float* fbn = fb + (size_t)(j + 1) * C * HW;

#pragma unroll
        for (int nt = 0; nt < 4; ++nt) {
            bf16x8 BH0, BL0, BH1, BL1;
            split8(F[nt * 4 + 0], F[nt * 4 + 1], BH0, BL0);   // px 0..31 half
            split8(F[nt * 4 + 2], F[nt * 4 + 3], BH1, BL1);   // px 32..63
            if (j < 3) {                                       // prefetch j+1
#pragma unroll
                for (int kh = 0; kh < 2; ++kh) {
                    const float* p = fbn + (size_t)(nt * 16) * HW + kh * 32;
                    F[nt * 4 + kh * 2 + 0] = *(const float4*)p;
                    F[nt * 4 + kh * 2 + 1] = *(const float4*)(p + 4);
                }
            }
            acc[0][nt] = __builtin_amdgcn_mfma_f32_16x16x32_bf16(A[0][0], BH0, acc[0][nt], 0, 0, 0);
            acc[1][nt] = __builtin_amdgcn_mfma_f32_16x16x32_bf16(A[0][1], BH0, acc[1][nt], 0, 0, 0);
            acc[0][nt] = __builtin_amdgcn_mfma_f32_16x16x32_bf16(A[0][0], BL0, acc[0][nt], 0, 0, 0);
            acc[1][nt] = __builtin_amdgcn_mfma_f32_16x16x32_bf16(A[0][1], BL0, acc[1][nt], 0, 0, 0);
            acc[0][nt] = __builtin_amdgcn_mfma_f32_16x16x32_bf16(A[1][0], BH1, acc[0][nt], 0, 0, 0);
            acc[1][nt] = __builtin_amdgcn_mfma_f32_16x16x32_bf16(A[1][1], BH1, acc[1][nt], 0, 0, 0);
            acc[0][nt] = __builtin_amdgcn_mfma_f32_16x16x32_bf16(A[1][0], BL1, acc[0][nt], 0, 0, 0);
            acc[1][nt] = __builtin_amdgcn_mfma_f32_16x16x32_bf16(A[1][1], BL1, acc[1][nt], 0, 0, 0);
        }
    }

    // ---- block reduce (D: class = mt*16 + q*4 + r, ch = nt*16 + n)
    for (int w = 0; w < 4; ++w) {
        if (wv == w) {
#pragma unroll
            for (int mt = 0; mt < 2; ++mt)
#pragma unroll
                for (int nt = 0; nt < 4; ++nt)
#pragma unroll
                    for (int r = 0; r < 4; ++r) {
                        const int idx = (mt * 16 + q * 4 + r) * 64 + nt * 16 + n;
                        if (w == 0) red[idx]  = acc[mt][nt][r];
                        else        red[idx] += acc[mt][nt][r];
                    }
        }
        __syncthreads();
    }
    for (int i = tid; i < 32 * 64; i += 256)
        atomicAdd(&k0p[i], red[i]);
}

// ---------------- Kernel 2: normalize prototypes --------------------------
__global__ __launch_bounds__(256) void k2_norm(
    const float* __restrict__ k0p, float* __restrict__ k0n)
{
    __shared__ float rn[K];
    const int tid  = threadIdx.x;
    const int lane = tid & 63;
    const int wv   = tid >> 6;
    for (int cls = wv; cls < K; cls += 4) {
        const float v = k0p[cls * 64 + lane];
        const float s = wave_reduce_f32(v * v);
        if (lane == 0) rn[cls] = 1.0f / fmaxf(sqrtf(s), EPS);
    }
    __syncthreads();
    for (int i = tid; i < K * 64; i += 256) k0n[i] = k0p[i] * rn[i >> 6];
}

// ---------------- Kernel 3: logits + log-softmax + masked NLL -------------
// 2 px/thread: 2048 blocks (8 waves/SIMD grid cap), ~95 VGPR (~5 resident),
// dwordx2 coalesced feat loads with 2-stage register pipeline.
__global__ __launch_bounds__(256) void k3_loss(
    const float* __restrict__ feat, const unsigned* __restrict__ pm,
    const float* __restrict__ k0n, float* __restrict__ loss_sum)
{
    __shared__ __align__(16) float w[K * 64];
    const int tid = threadIdx.x;
    for (int i = tid; i < K * 64; i += 256) w[i] = k0n[i];
    __syncthreads();

    const int g   = blockIdx.x * 256 + tid;
    const int px0 = g << 1;
    const int b   = px0 >> 18;
    const int hw  = px0 & (HW - 1);
    const float* fb = feat + (size_t)b * C * HW + hw;

    const uint2 mv = *(const uint2*)(pm + px0);

    float2 dot[K];
#pragma unroll
    for (int k = 0; k < K; ++k) dot[k] = make_float2(0.f, 0.f);
    float2 ss = make_float2(0.f, 0.f);

    float2 f[8];
#pragma unroll
    for (int j = 0; j < 8; ++j)
        f[j] = *(const float2*)(fb + (size_t)j * HW);

#pragma unroll
    for (int cg = 0; cg < 64; cg += 8) {
        float2 gq[8];
        if (cg + 8 < 64) {
#pragma unroll
            for (int j = 0; j < 8; ++j)
                gq[j] = *(const float2*)(fb + (size_t)(cg + 8 + j) * HW);
        }
#pragma unroll
        for (int j = 0; j < 8; ++j) {
            ss.x = fmaf(f[j].x, f[j].x, ss.x);
            ss.y = fmaf(f[j].y, f[j].y, ss.y);
        }
#pragma unroll
        for (int k = 0; k < K; ++k) {
            const float4 wa = *(const float4*)&w[k * 64 + cg];
            const float4 wb = *(const float4*)&w[k * 64 + cg + 4];
            float2 d = dot[k];
            d.x = fmaf(f[0].x, wa.x, d.x); d.y = fmaf(f[0].y, wa.x, d.y);
            d.x = fmaf(f[1].x, wa.y, d.x); d.y = fmaf(f[1].y, wa.y, d.y);
            d.x = fmaf(f[2].x, wa.z, d.x); d.y = fmaf(f[2].y, wa.z, d.y);
            d.x = fmaf(f[3].x, wa.w, d.x); d.y = fmaf(f[3].y, wa.w, d.y);
            d.x = fmaf(f[4].x, wb.x, d.x); d.y = fmaf(f[4].y, wb.x, d.y);
            d.x = fmaf(f[5].x, wb.y, d.x); d.y = fmaf(f[5].y, wb.y, d.y);
            d.x = fmaf(f[6].x, wb.z, d.x); d.y = fmaf(f[6].y, wb.z, d.y);
            d.x = fmaf(f[7].x, wb.w, d.x); d.y = fmaf(f[7].y, wb.w, d.y);
            dot[k] = d;
        }
        if (cg + 8 < 64) {
#pragma unroll
            for (int j = 0; j < 8; ++j) f[j] = gq[j];
        }
    }

    float ls = 0.0f;
    float* dp = (float*)&dot[0];              // dp[k*2 + comp]
    const float sarr[2] = {ss.x, ss.y};
    const unsigned marr[2] = {mv.x, mv.y};
#pragma unroll
    for (int comp = 0; comp < 2; ++comp) {
        const float sc = TAUINV / fmaxf(sqrtf(sarr[comp]), EPS);
        float mx = -1e30f;
#pragma unroll
        for (int k = 0; k < K; ++k) {
            dp[k * 2 + comp] *= sc;
            mx = fmaxf(mx, dp[k * 2 + comp]);
        }
        float se = 0.0f;
#pragma unroll
        for (int k = 0; k < K; ++k) se += expf(dp[k * 2 + comp] - mx);
        const float logZ = mx + logf(se);
        const unsigned m = marr[comp];
        ls += (float)__popc(m) * logZ;
#pragma unroll
        for (int k = 0; k < K; ++k) {
            const int s = ((int)(m << (31 - k))) >> 31;
            ls -= __int_as_float(s & __float_as_int(dp[k * 2 + comp]));
        }
    }

    ls = wave_reduce_f32(ls);
    if ((tid & 63) == 0) atomicAdd(loss_sum, ls);
}

// ---------------- Kernel 4: finalize --------------------------------------
__global__ void k4_final(const float* __restrict__ loss_sum,
                         const unsigned* __restrict__ num_pos,
                         float* __restrict__ out)
{
    out[0] = loss_sum[0] / (float)num_pos[0];
}

// ---------------- launch ---------------------------------------------------
extern "C" void kernel_launch(void* const* d_in, const int* in_sizes, int n_in,
                              void* d_out, int out_size, void* d_ws, size_t ws_size,
                              hipStream_t stream)
{
    const float* feat = (const float*)d_in[0];
    const int*   gt   = (const int*)d_in[1];
    float*       out  = (float*)d_out;

    char* ws = (char*)d_ws;
    unsigned* num_pos  = (unsigned*)(ws + 0);
    float*    loss_sum = (float*)(ws + 4);
    float*    k0p      = (float*)(ws + 256);    // [32][64]
    float*    k0n      = (float*)(ws + 8448);   // [19][64]
    unsigned* pm       = (unsigned*)(ws + 65536);

    hipMemsetAsync(d_ws, 0, 16384, stream);     // zero num_pos/loss_sum/k0p

    k0_mask<<<NPIX / 1024, 256, 0, stream>>>(gt, pm, num_pos);
    k1_proto<<<1024,       256, 0, stream>>>(feat, pm, k0p);
    k2_norm <<<1,          256, 0, stream>>>(k0p, k0n);
    k3_loss <<<NPIX / 512, 256, 0, stream>>>(feat, pm, k0n, loss_sum);
    k4_final<<<1, 1, 0, stream>>>(loss_sum, num_pos, out);
}